// Round 1
// baseline (237.097 us; speedup 1.0000x reference)
//
#include <hip/hip_runtime.h>
#include <hip/hip_bf16.h>

typedef __bf16 bf16x8 __attribute__((ext_vector_type(8)));
typedef float f32x4 __attribute__((ext_vector_type(4)));
typedef unsigned short u16;
typedef unsigned int u32;
typedef u16 u16x8 __attribute__((ext_vector_type(8)));

#define LOG2E 1.4426950408889634f

// f32 -> bf16 round-to-nearest-even, manual (no __bf16 scalar dependence)
__device__ inline u16 tobf(float f) {
  u32 u = __builtin_bit_cast(u32, f);
  u32 r = (u + 0x7fffu + ((u >> 16) & 1u)) >> 16;
  return (u16)r;
}

__device__ inline void gload_lds16(const void* g, void* lds) {
  __builtin_amdgcn_global_load_lds(
      (const __attribute__((address_space(1))) u32*)g,
      (__attribute__((address_space(3))) u32*)lds, 16, 0, 0);
}

// ---------------- convert x (f32 -> bf16), 8 elems/thread ----------------
__global__ void convert_f32_bf16(const float* __restrict__ in,
                                 u16* __restrict__ out, int n8) {
  int i = blockIdx.x * blockDim.x + threadIdx.x;
  int stride = gridDim.x * blockDim.x;
  for (; i < n8; i += stride) {
    const float4* p = (const float4*)in + (size_t)i * 2;
    float4 a = p[0], b = p[1];
    u16x8 v;
    v[0] = tobf(a.x); v[1] = tobf(a.y); v[2] = tobf(a.z); v[3] = tobf(a.w);
    v[4] = tobf(b.x); v[5] = tobf(b.y); v[6] = tobf(b.z); v[7] = tobf(b.w);
    *(u16x8*)(out + (size_t)i * 8) = v;
  }
}

// ---------------- transpose + cast weights: out[n][k] = in[k][n] ----------
__global__ void transpose_w(const float* __restrict__ in,
                            u16* __restrict__ out, int K, int N) {
  __shared__ float tile[32][33];
  int nbx = N >> 5;
  int bx = blockIdx.x % nbx, by = blockIdx.x / nbx;
  int k0 = by << 5, n0 = bx << 5;
  int tx = threadIdx.x & 31, ty = threadIdx.x >> 5;
#pragma unroll
  for (int j = 0; j < 4; ++j) {
    int row = ty + j * 8;
    tile[row][tx] = in[(size_t)(k0 + row) * N + n0 + tx];
  }
  __syncthreads();
#pragma unroll
  for (int j = 0; j < 4; ++j) {
    int row = ty + j * 8;
    out[(size_t)(n0 + row) * K + k0 + tx] = tobf(tile[tx][row]);
  }
}

// ---------------- GEMM: C[M,N] = A[M,K] * Bt[N,K]^T  (bf16 in, f32 acc) ---
// 128x128 tile, BK=64, 256 thr (4 waves, 2x2), 64x64 per wave.
// LDS staged via global_load_lds w16, XOR swizzle via pre-swizzled source.
// EPI 0: scatter q/k/vT bf16 (+bias). EPI 1: f32 out (+bias).
template <int EPI>
__global__ __launch_bounds__(256) void gemm_bt(
    const u16* __restrict__ A, const u16* __restrict__ Bt,
    const float* __restrict__ bias,
    u16* __restrict__ o0, u16* __restrict__ o1, u16* __restrict__ o2,
    float* __restrict__ fo, int M, int N, int K) {
  __shared__ __align__(16) u16 As[128 * 64];
  __shared__ __align__(16) u16 Bs[128 * 64];
  const int tid = threadIdx.x;
  const int lane = tid & 63;
  const int wave = tid >> 6;
  const int nbn = N >> 7;
  const int bm = (int)blockIdx.x / nbn, bn = (int)blockIdx.x % nbn;
  const int m0 = bm << 7, n0 = bn << 7;
  const int wr = wave >> 1, wc = wave & 1;
  const int r15 = lane & 15, g = lane >> 4;

  f32x4 acc[4][4] = {};

  const int nkt = K >> 6;
  for (int kt = 0; kt < nkt; ++kt) {
#pragma unroll
    for (int j = 0; j < 4; ++j) {
      int c = j * 4 + wave;
      int byte0 = c * 1024 + lane * 16;
      int row = byte0 >> 7;
      int colb = (byte0 & 127) ^ ((row & 7) << 4);
      gload_lds16(A + (size_t)(m0 + row) * K + kt * 64 + (colb >> 1),
                  (char*)As + c * 1024);
      gload_lds16(Bt + (size_t)(n0 + row) * K + kt * 64 + (colb >> 1),
                  (char*)Bs + c * 1024);
    }
    __syncthreads();
#pragma unroll
    for (int kk = 0; kk < 64; kk += 32) {
      bf16x8 af[4], bf[4];
#pragma unroll
      for (int i = 0; i < 4; ++i) {
        int rowA = wr * 64 + i * 16 + r15;
        int ca = (kk * 2 + 16 * g) ^ ((rowA & 7) << 4);
        af[i] = *(const bf16x8*)((const char*)As + rowA * 128 + ca);
        int rowB = wc * 64 + i * 16 + r15;
        int cb = (kk * 2 + 16 * g) ^ ((rowB & 7) << 4);
        bf[i] = *(const bf16x8*)((const char*)Bs + rowB * 128 + cb);
      }
#pragma unroll
      for (int i = 0; i < 4; ++i)
#pragma unroll
        for (int j2 = 0; j2 < 4; ++j2)
          acc[i][j2] = __builtin_amdgcn_mfma_f32_16x16x32_bf16(
              af[i], bf[j2], acc[i][j2], 0, 0, 0);
    }
    __syncthreads();
  }
  // epilogue: D layout col=lane&15, row=(lane>>4)*4+rr
#pragma unroll
  for (int j2 = 0; j2 < 4; ++j2) {
    int n = n0 + wc * 64 + j2 * 16 + r15;
    float bv = bias[n];
#pragma unroll
    for (int i = 0; i < 4; ++i) {
      int mbase = m0 + wr * 64 + i * 16 + g * 4;
#pragma unroll
      for (int rr = 0; rr < 4; ++rr) {
        float val = acc[i][j2][rr] + bv;
        int m = mbase + rr;
        if (EPI == 0) {
          u16 hv = tobf(val);
          int b = m >> 11, t = m & 2047;
          int sec = n >> 10, nn = n & 1023;
          int h = nn >> 6, d = nn & 63;
          if (sec == 0)
            o0[((size_t)((b * 16 + h) * 2048 + t)) * 64 + d] = hv;
          else if (sec == 1)
            o1[((size_t)((b * 16 + h) * 2048 + t)) * 64 + d] = hv;
          else
            o2[((size_t)((b * 16 + h) * 64 + d)) * 2048 + t] = hv;
        } else {
          fo[(size_t)m * N + n] = val;
        }
      }
    }
  }
}

// ---------------- causal flash attention ---------------------------------
// grid (qt=32, bh=32), 256 thr / 4 waves; wave owns 16 q-rows; KV tiles 64.
__global__ __launch_bounds__(256) void attn_kernel(
    const u16* __restrict__ qb, const u16* __restrict__ kb,
    const u16* __restrict__ vt, u16* __restrict__ yb) {
  __shared__ __align__(16) u16 Ks[64 * 64];
  __shared__ __align__(16) u16 Vs[64 * 64];
  __shared__ __align__(16) u16 Ps[4][16 * 80];
  const int tid = threadIdx.x;
  const int lane = tid & 63;
  const int w = tid >> 6;
  const int r15 = lane & 15, g = lane >> 4;
  const int qt = blockIdx.x;
  const int bh = blockIdx.y;

  // Q fragments (held in regs all kernel)
  const int tq = qt * 64 + w * 16 + r15;
  const u16* qrow = qb + ((size_t)bh * 2048 + tq) * 64;
  bf16x8 aq[2];
  aq[0] = *(const bf16x8*)(qrow + 8 * g);
  aq[1] = *(const bf16x8*)(qrow + 32 + 8 * g);

  f32x4 o[4] = {};
  float mrow[4] = {-INFINITY, -INFINITY, -INFINITY, -INFINITY};
  float lrow[4] = {0.f, 0.f, 0.f, 0.f};

  for (int kt = 0; kt <= qt; ++kt) {
    // stage K [64 kv][64 d] and V^T [64 d][64 kv] (8 KB each)
#pragma unroll
    for (int j = 0; j < 2; ++j) {
      int c = j * 4 + w;
      int byte0 = c * 1024 + lane * 16;
      int row = byte0 >> 7;
      int colb = (byte0 & 127) ^ ((row & 7) << 4);
      gload_lds16(kb + ((size_t)bh * 2048 + kt * 64 + row) * 64 + (colb >> 1),
                  (char*)Ks + c * 1024);
      gload_lds16(vt + ((size_t)bh * 64 + row) * 2048 + kt * 64 + (colb >> 1),
                  (char*)Vs + c * 1024);
    }
    __syncthreads();

    // S = Q K^T  (16 q x 64 kv per wave)
    f32x4 s[4] = {};
#pragma unroll
    for (int kk = 0; kk < 2; ++kk) {
#pragma unroll
      for (int nb = 0; nb < 4; ++nb) {
        int rowK = nb * 16 + r15;
        int cb = (kk * 64 + 16 * g) ^ ((rowK & 7) << 4);
        bf16x8 bk = *(const bf16x8*)((const char*)Ks + rowK * 128 + cb);
        s[nb] = __builtin_amdgcn_mfma_f32_16x16x32_bf16(aq[kk], bk, s[nb], 0, 0, 0);
      }
    }

    const bool diag = (kt == qt);
    float p[4][4];
    float mt[4] = {-INFINITY, -INFINITY, -INFINITY, -INFINITY};
#pragma unroll
    for (int nb = 0; nb < 4; ++nb) {
#pragma unroll
      for (int rr = 0; rr < 4; ++rr) {
        float sv = s[nb][rr] * 0.125f;
        if (diag) {
          int kvl = nb * 16 + r15;
          int ql = w * 16 + g * 4 + rr;
          if (kvl > ql) sv = -INFINITY;
        }
        p[nb][rr] = sv;
        mt[rr] = fmaxf(mt[rr], sv);
      }
    }
    // reduce row-max across the 16-lane column group
#pragma unroll
    for (int rr = 0; rr < 4; ++rr) {
      float v = mt[rr];
      v = fmaxf(v, __shfl_xor(v, 1, 64));
      v = fmaxf(v, __shfl_xor(v, 2, 64));
      v = fmaxf(v, __shfl_xor(v, 4, 64));
      v = fmaxf(v, __shfl_xor(v, 8, 64));
      mt[rr] = v;
    }
    u16* pw = &Ps[w][0];
#pragma unroll
    for (int rr = 0; rr < 4; ++rr) {
      float mnew = fmaxf(mrow[rr], mt[rr]);
      float alpha = exp2f((mrow[rr] - mnew) * LOG2E);
      mrow[rr] = mnew;
      float srow = 0.f;
#pragma unroll
      for (int nb = 0; nb < 4; ++nb) {
        float pv = exp2f((p[nb][rr] - mnew) * LOG2E);
        p[nb][rr] = pv;
        srow += pv;
      }
      srow += __shfl_xor(srow, 1, 64);
      srow += __shfl_xor(srow, 2, 64);
      srow += __shfl_xor(srow, 4, 64);
      srow += __shfl_xor(srow, 8, 64);
      lrow[rr] = lrow[rr] * alpha + srow;
#pragma unroll
      for (int db = 0; db < 4; ++db) o[db][rr] *= alpha;
      // write P (bf16) to per-wave LDS, [16 q][80 kv-pad]
#pragma unroll
      for (int nb = 0; nb < 4; ++nb)
        pw[(g * 4 + rr) * 80 + nb * 16 + r15] = tobf(p[nb][rr]);
    }
    // PV: o += P * V   (A-frag from P LDS, B-frag from swizzled V^T)
#pragma unroll
    for (int kk = 0; kk < 2; ++kk) {
      bf16x8 ap = *(const bf16x8*)((const char*)pw + r15 * 160 + kk * 64 + 16 * g);
#pragma unroll
      for (int db = 0; db < 4; ++db) {
        int rowV = db * 16 + r15;
        int cb = (kk * 64 + 16 * g) ^ ((rowV & 7) << 4);
        bf16x8 bv = *(const bf16x8*)((const char*)Vs + rowV * 128 + cb);
        o[db] = __builtin_amdgcn_mfma_f32_16x16x32_bf16(ap, bv, o[db], 0, 0, 0);
      }
    }
    __syncthreads();
  }

  // epilogue: y[b, t, h*64+d] bf16
  int b = bh >> 4, h = bh & 15;
#pragma unroll
  for (int db = 0; db < 4; ++db) {
#pragma unroll
    for (int rr = 0; rr < 4; ++rr) {
      int t = qt * 64 + w * 16 + g * 4 + rr;
      int c = h * 64 + db * 16 + r15;
      yb[((size_t)b * 2048 + t) * 1024 + c] = tobf(o[db][rr] / lrow[rr]);
    }
  }
}

extern "C" void kernel_launch(void* const* d_in, const int* in_sizes, int n_in,
                              void* d_out, int out_size, void* d_ws,
                              size_t ws_size, hipStream_t stream) {
  const float* x = (const float*)d_in[0];
  const float* w_attn = (const float*)d_in[1];
  const float* b_attn = (const float*)d_in[2];
  const float* w_proj = (const float*)d_in[3];
  const float* b_proj = (const float*)d_in[4];
  float* out = (float*)d_out;
  char* ws = (char*)d_ws;

  u16* xb = (u16*)ws;                          // 8 MB  [4096][1024]
  u16* wat = (u16*)(ws + (8ull << 20));        // 6 MB  [3072][1024]
  u16* wpt = (u16*)(ws + (14ull << 20));       // 2 MB  [1024][1024]
  u16* qbuf = (u16*)(ws + (16ull << 20));      // 8 MB  [B,H,T,D]
  u16* kbuf = (u16*)(ws + (24ull << 20));      // 8 MB  [B,H,T,D]
  u16* vtb = (u16*)(ws + (32ull << 20));       // 8 MB  [B,H,D,T]
  u16* yb = (u16*)(ws + (40ull << 20));        // 8 MB  [4096][1024]

  convert_f32_bf16<<<2048, 256, 0, stream>>>(x, xb, (4096 * 1024) / 8);
  transpose_w<<<3072, 256, 0, stream>>>(w_attn, wat, 1024, 3072);
  transpose_w<<<1024, 256, 0, stream>>>(w_proj, wpt, 1024, 1024);
  gemm_bt<0><<<32 * 24, 256, 0, stream>>>(xb, wat, b_attn, qbuf, kbuf, vtb,
                                          nullptr, 4096, 3072, 1024);
  attn_kernel<<<dim3(32, 32), 256, 0, stream>>>(qbuf, kbuf, vtb, yb);
  gemm_bt<1><<<32 * 8, 256, 0, stream>>>(yb, wpt, b_proj, nullptr, nullptr,
                                         nullptr, out, 4096, 1024, 1024);
}

// Round 2
// 177.471 us; speedup vs baseline: 1.3360x; 1.3360x over previous
//
#include <hip/hip_runtime.h>
#include <hip/hip_bf16.h>

typedef __bf16 bf16x8 __attribute__((ext_vector_type(8)));
typedef float f32x4 __attribute__((ext_vector_type(4)));
typedef unsigned short u16;
typedef unsigned int u32;
typedef u16 u16x8 __attribute__((ext_vector_type(8)));

#define SM_SCALE 0.1803368801111244f  // (1/8) * log2(e)

// f32 -> bf16 round-to-nearest-even
__device__ inline u16 tobf(float f) {
  u32 u = __builtin_bit_cast(u32, f);
  u32 r = (u + 0x7fffu + ((u >> 16) & 1u)) >> 16;
  return (u16)r;
}

__device__ inline void gload_lds16(const void* g, void* lds) {
  __builtin_amdgcn_global_load_lds(
      (const __attribute__((address_space(1))) u32*)g,
      (__attribute__((address_space(3))) u32*)lds, 16, 0, 0);
}

// ---------------- convert x (f32 -> bf16), 8 elems/thread ----------------
__global__ void convert_f32_bf16(const float* __restrict__ in,
                                 u16* __restrict__ out, int n8) {
  int i = blockIdx.x * blockDim.x + threadIdx.x;
  int stride = gridDim.x * blockDim.x;
  for (; i < n8; i += stride) {
    const float4* p = (const float4*)in + (size_t)i * 2;
    float4 a = p[0], b = p[1];
    u16x8 v;
    v[0] = tobf(a.x); v[1] = tobf(a.y); v[2] = tobf(a.z); v[3] = tobf(a.w);
    v[4] = tobf(b.x); v[5] = tobf(b.y); v[6] = tobf(b.z); v[7] = tobf(b.w);
    *(u16x8*)(out + (size_t)i * 8) = v;
  }
}

// ---------------- transpose + cast weights: out[n][k] = in[k][n] ----------
__global__ void transpose_w(const float* __restrict__ in,
                            u16* __restrict__ out, int K, int N) {
  __shared__ float tile[32][33];
  int nbx = N >> 5;
  int bx = blockIdx.x % nbx, by = blockIdx.x / nbx;
  int k0 = by << 5, n0 = bx << 5;
  int tx = threadIdx.x & 31, ty = threadIdx.x >> 5;
#pragma unroll
  for (int j = 0; j < 4; ++j) {
    int row = ty + j * 8;
    tile[row][tx] = in[(size_t)(k0 + row) * N + n0 + tx];
  }
  __syncthreads();
#pragma unroll
  for (int j = 0; j < 4; ++j) {
    int row = ty + j * 8;
    out[(size_t)(n0 + row) * K + k0 + tx] = tobf(tile[tx][row]);
  }
}

// ---------------- GEMM: C[M,N] = A[M,K] * Bt[N,K]^T  (bf16 in, f32 acc) ---
template <int EPI>
__global__ __launch_bounds__(256) void gemm_bt(
    const u16* __restrict__ A, const u16* __restrict__ Bt,
    const float* __restrict__ bias,
    u16* __restrict__ o0, u16* __restrict__ o1, u16* __restrict__ o2,
    float* __restrict__ fo, int M, int N, int K) {
  __shared__ __align__(16) u16 As[128 * 64];
  __shared__ __align__(16) u16 Bs[128 * 64];
  const int tid = threadIdx.x;
  const int lane = tid & 63;
  const int wave = tid >> 6;
  const int nbn = N >> 7;
  const int bm = (int)blockIdx.x / nbn, bn = (int)blockIdx.x % nbn;
  const int m0 = bm << 7, n0 = bn << 7;
  const int wr = wave >> 1, wc = wave & 1;
  const int r15 = lane & 15, g = lane >> 4;

  f32x4 acc[4][4] = {};

  const int nkt = K >> 6;
  for (int kt = 0; kt < nkt; ++kt) {
#pragma unroll
    for (int j = 0; j < 4; ++j) {
      int c = j * 4 + wave;
      int byte0 = c * 1024 + lane * 16;
      int row = byte0 >> 7;
      int colb = (byte0 & 127) ^ ((row & 7) << 4);
      gload_lds16(A + (size_t)(m0 + row) * K + kt * 64 + (colb >> 1),
                  (char*)As + c * 1024);
      gload_lds16(Bt + (size_t)(n0 + row) * K + kt * 64 + (colb >> 1),
                  (char*)Bs + c * 1024);
    }
    __syncthreads();
#pragma unroll
    for (int kk = 0; kk < 64; kk += 32) {
      bf16x8 af[4], bf[4];
#pragma unroll
      for (int i = 0; i < 4; ++i) {
        int rowA = wr * 64 + i * 16 + r15;
        int ca = (kk * 2 + 16 * g) ^ ((rowA & 7) << 4);
        af[i] = *(const bf16x8*)((const char*)As + rowA * 128 + ca);
        int rowB = wc * 64 + i * 16 + r15;
        int cb = (kk * 2 + 16 * g) ^ ((rowB & 7) << 4);
        bf[i] = *(const bf16x8*)((const char*)Bs + rowB * 128 + cb);
      }
#pragma unroll
      for (int i = 0; i < 4; ++i)
#pragma unroll
        for (int j2 = 0; j2 < 4; ++j2)
          acc[i][j2] = __builtin_amdgcn_mfma_f32_16x16x32_bf16(
              af[i], bf[j2], acc[i][j2], 0, 0, 0);
    }
    __syncthreads();
  }
#pragma unroll
  for (int j2 = 0; j2 < 4; ++j2) {
    int n = n0 + wc * 64 + j2 * 16 + r15;
    float bv = bias[n];
#pragma unroll
    for (int i = 0; i < 4; ++i) {
      int mbase = m0 + wr * 64 + i * 16 + g * 4;
#pragma unroll
      for (int rr = 0; rr < 4; ++rr) {
        float val = acc[i][j2][rr] + bv;
        int m = mbase + rr;
        if (EPI == 0) {
          u16 hv = tobf(val);
          int b = m >> 11, t = m & 2047;
          int sec = n >> 10, nn = n & 1023;
          int h = nn >> 6, d = nn & 63;
          if (sec == 0)
            o0[((size_t)((b * 16 + h) * 2048 + t)) * 64 + d] = hv;
          else if (sec == 1)
            o1[((size_t)((b * 16 + h) * 2048 + t)) * 64 + d] = hv;
          else
            o2[((size_t)((b * 16 + h) * 64 + d)) * 2048 + t] = hv;
        } else {
          fo[(size_t)m * N + n] = val;
        }
      }
    }
  }
}

// ---------------- causal flash attention v2 -------------------------------
// 512 thr / 8 waves; wave owns 16 q-rows (128 q/block); KV tiles 64;
// double-buffered K/V staging; per-wave skip of fully-masked tail tiles;
// defer-max (THR=8). Grid: 512 blocks, heavy chunks issued first so
// (bx, bx+256) pairs have complementary work.
__global__ __launch_bounds__(512) void attn_kernel(
    const u16* __restrict__ qb, const u16* __restrict__ kb,
    const u16* __restrict__ vt, u16* __restrict__ yb) {
  __shared__ __align__(16) u16 Ks[2][64 * 64];
  __shared__ __align__(16) u16 Vs[2][64 * 64];
  __shared__ __align__(16) u16 Ps[8][16 * 80];
  const int tid = threadIdx.x;
  const int lane = tid & 63;
  const int w = tid >> 6;
  const int r15 = lane & 15, g = lane >> 4;
  const int bx = blockIdx.x;
  const int kk16 = bx >> 5;                      // 0..15
  const int c = (kk16 < 8) ? (15 - kk16) : (kk16 - 8);  // heavy chunks first
  const int bh = bx & 31;

  const int qmin = c * 128 + w * 16;             // wave's first q row
  const int qmax = qmin + 15;
  const int nt = 2 * c + 2;                      // KV tiles to process

  // staging addresses (per thread: 16B, row = tid>>3, pre-swizzled source)
  const int srow = tid >> 3;
  const int sb0 = (tid * 16) & 127;
  const int scolb = sb0 ^ ((srow & 7) << 4);
  const u16* ksrc = kb + ((size_t)bh * 2048 + srow) * 64 + (scolb >> 1);
  const u16* vsrc = vt + ((size_t)bh * 64 + srow) * 2048 + (scolb >> 1);

#define STAGE(buf, kt)                                             \
  do {                                                             \
    gload_lds16(ksrc + (size_t)(kt) * 4096, (char*)Ks[buf] + w * 1024); \
    gload_lds16(vsrc + (kt) * 64, (char*)Vs[buf] + w * 1024);      \
  } while (0)

  // Q fragments (regs all kernel)
  const u16* qrow = qb + ((size_t)bh * 2048 + qmin + r15) * 64;
  bf16x8 aq[2];
  aq[0] = *(const bf16x8*)(qrow + 8 * g);
  aq[1] = *(const bf16x8*)(qrow + 32 + 8 * g);

  f32x4 o[4] = {};
  float mrow[4] = {-INFINITY, -INFINITY, -INFINITY, -INFINITY};
  float lrow[4] = {0.f, 0.f, 0.f, 0.f};

  STAGE(0, 0);
  __syncthreads();
  int cur = 0;
  for (int kt = 0; kt < nt; ++kt) {
    if (kt + 1 < nt) STAGE(cur ^ 1, kt + 1);
    if (kt * 64 <= qmax) {
      const char* Kc = (const char*)Ks[cur];
      const char* Vc = (const char*)Vs[cur];
      // S = Q K^T  (16 q x 64 kv per wave); lane holds q=(g*4+rr), kv=nb*16+r15
      f32x4 s[4] = {};
#pragma unroll
      for (int kk = 0; kk < 2; ++kk) {
#pragma unroll
        for (int nb = 0; nb < 4; ++nb) {
          int rowK = nb * 16 + r15;
          int cb = (kk * 64 + 16 * g) ^ ((rowK & 7) << 4);
          bf16x8 bk = *(const bf16x8*)(Kc + rowK * 128 + cb);
          s[nb] = __builtin_amdgcn_mfma_f32_16x16x32_bf16(aq[kk], bk, s[nb], 0, 0, 0);
        }
      }

      const bool anymask = (kt * 64 + 63 > qmin);
      float p[4][4];
      float mt[4] = {-INFINITY, -INFINITY, -INFINITY, -INFINITY};
#pragma unroll
      for (int nb = 0; nb < 4; ++nb) {
#pragma unroll
        for (int rr = 0; rr < 4; ++rr) {
          float sv = s[nb][rr] * SM_SCALE;  // log2-domain
          if (anymask) {
            int kvg = kt * 64 + nb * 16 + r15;
            int qg = qmin + g * 4 + rr;
            if (kvg > qg) sv = -INFINITY;
          }
          p[nb][rr] = sv;
          mt[rr] = fmaxf(mt[rr], sv);
        }
      }
#pragma unroll
      for (int rr = 0; rr < 4; ++rr) {
        float v = mt[rr];
        v = fmaxf(v, __shfl_xor(v, 1, 64));
        v = fmaxf(v, __shfl_xor(v, 2, 64));
        v = fmaxf(v, __shfl_xor(v, 4, 64));
        v = fmaxf(v, __shfl_xor(v, 8, 64));
        mt[rr] = v;
      }
      // defer-max: only rescale when a row grew by > 8 (log2-domain)
      bool grew = false;
#pragma unroll
      for (int rr = 0; rr < 4; ++rr) grew |= (mt[rr] > mrow[rr] + 8.f);
      if (__any(grew)) {
#pragma unroll
        for (int rr = 0; rr < 4; ++rr) {
          float mnew = fmaxf(mrow[rr], mt[rr]);
          float alpha = exp2f(mrow[rr] - mnew);
          mrow[rr] = mnew;
          lrow[rr] *= alpha;
#pragma unroll
          for (int db = 0; db < 4; ++db) o[db][rr] *= alpha;
        }
      }
      u16* pw = &Ps[w][0];
#pragma unroll
      for (int rr = 0; rr < 4; ++rr) {
        float srowv = 0.f;
#pragma unroll
        for (int nb = 0; nb < 4; ++nb) {
          float pv = exp2f(p[nb][rr] - mrow[rr]);
          p[nb][rr] = pv;
          srowv += pv;
        }
        srowv += __shfl_xor(srowv, 1, 64);
        srowv += __shfl_xor(srowv, 2, 64);
        srowv += __shfl_xor(srowv, 4, 64);
        srowv += __shfl_xor(srowv, 8, 64);
        lrow[rr] += srowv;
#pragma unroll
        for (int nb = 0; nb < 4; ++nb)
          pw[(g * 4 + rr) * 80 + nb * 16 + r15] = tobf(p[nb][rr]);
      }
      // PV: o += P * V
#pragma unroll
      for (int kk = 0; kk < 2; ++kk) {
        bf16x8 ap = *(const bf16x8*)((const char*)pw + r15 * 160 + kk * 64 + 16 * g);
#pragma unroll
        for (int db = 0; db < 4; ++db) {
          int rowV = db * 16 + r15;
          int cb = (kk * 64 + 16 * g) ^ ((rowV & 7) << 4);
          bf16x8 bv = *(const bf16x8*)(Vc + rowV * 128 + cb);
          o[db] = __builtin_amdgcn_mfma_f32_16x16x32_bf16(ap, bv, o[db], 0, 0, 0);
        }
      }
    }
    __syncthreads();
    cur ^= 1;
  }
#undef STAGE

  // epilogue: y[b, t, h*64+d] bf16
  int b = bh >> 4, h = bh & 15;
#pragma unroll
  for (int db = 0; db < 4; ++db) {
#pragma unroll
    for (int rr = 0; rr < 4; ++rr) {
      int t = qmin + g * 4 + rr;
      int col = h * 64 + db * 16 + r15;
      yb[((size_t)b * 2048 + t) * 1024 + col] = tobf(o[db][rr] / lrow[rr]);
    }
  }
}

extern "C" void kernel_launch(void* const* d_in, const int* in_sizes, int n_in,
                              void* d_out, int out_size, void* d_ws,
                              size_t ws_size, hipStream_t stream) {
  const float* x = (const float*)d_in[0];
  const float* w_attn = (const float*)d_in[1];
  const float* b_attn = (const float*)d_in[2];
  const float* w_proj = (const float*)d_in[3];
  const float* b_proj = (const float*)d_in[4];
  float* out = (float*)d_out;
  char* ws = (char*)d_ws;

  u16* xb = (u16*)ws;                          // 8 MB  [4096][1024]
  u16* wat = (u16*)(ws + (8ull << 20));        // 6 MB  [3072][1024]
  u16* wpt = (u16*)(ws + (14ull << 20));       // 2 MB  [1024][1024]
  u16* qbuf = (u16*)(ws + (16ull << 20));      // 8 MB  [B,H,T,D]
  u16* kbuf = (u16*)(ws + (24ull << 20));      // 8 MB  [B,H,T,D]
  u16* vtb = (u16*)(ws + (32ull << 20));       // 8 MB  [B,H,D,T]
  u16* yb = (u16*)(ws + (40ull << 20));        // 8 MB  [4096][1024]

  convert_f32_bf16<<<2048, 256, 0, stream>>>(x, xb, (4096 * 1024) / 8);
  transpose_w<<<3072, 256, 0, stream>>>(w_attn, wat, 1024, 3072);
  transpose_w<<<1024, 256, 0, stream>>>(w_proj, wpt, 1024, 1024);
  gemm_bt<0><<<32 * 24, 256, 0, stream>>>(xb, wat, b_attn, qbuf, kbuf, vtb,
                                          nullptr, 4096, 3072, 1024);
  attn_kernel<<<512, 512, 0, stream>>>(qbuf, kbuf, vtb, yb);
  gemm_bt<1><<<32 * 8, 256, 0, stream>>>(yb, wpt, b_proj, nullptr, nullptr,
                                         nullptr, out, 4096, 1024, 1024);
}

// Round 3
// 162.302 us; speedup vs baseline: 1.4608x; 1.0935x over previous
//
#include <hip/hip_runtime.h>
#include <hip/hip_bf16.h>

typedef __bf16 bf16x8 __attribute__((ext_vector_type(8)));
typedef float f32x4 __attribute__((ext_vector_type(4)));
typedef unsigned short u16;
typedef unsigned int u32;
typedef u16 u16x8 __attribute__((ext_vector_type(8)));

#define SM_SCALE 0.1803368801111244f  // (1/8) * log2(e)

// f32 -> bf16 round-to-nearest-even
__device__ inline u16 tobf(float f) {
  u32 u = __builtin_bit_cast(u32, f);
  u32 r = (u + 0x7fffu + ((u >> 16) & 1u)) >> 16;
  return (u16)r;
}

__device__ inline void gload_lds16(const void* g, void* lds) {
  __builtin_amdgcn_global_load_lds(
      (const __attribute__((address_space(1))) u32*)g,
      (__attribute__((address_space(3))) u32*)lds, 16, 0, 0);
}

// ---------------- convert x (f32 -> bf16), 8 elems/thread ----------------
__global__ void convert_f32_bf16(const float* __restrict__ in,
                                 u16* __restrict__ out, int n8) {
  int i = blockIdx.x * blockDim.x + threadIdx.x;
  int stride = gridDim.x * blockDim.x;
  for (; i < n8; i += stride) {
    const float4* p = (const float4*)in + (size_t)i * 2;
    float4 a = p[0], b = p[1];
    u16x8 v;
    v[0] = tobf(a.x); v[1] = tobf(a.y); v[2] = tobf(a.z); v[3] = tobf(a.w);
    v[4] = tobf(b.x); v[5] = tobf(b.y); v[6] = tobf(b.z); v[7] = tobf(b.w);
    *(u16x8*)(out + (size_t)i * 8) = v;
  }
}

// ---------------- transpose + cast weights: out[n][k] = in[k][n] ----------
__global__ void transpose_w(const float* __restrict__ in,
                            u16* __restrict__ out, int K, int N) {
  __shared__ float tile[32][33];
  int nbx = N >> 5;
  int bx = blockIdx.x % nbx, by = blockIdx.x / nbx;
  int k0 = by << 5, n0 = bx << 5;
  int tx = threadIdx.x & 31, ty = threadIdx.x >> 5;
#pragma unroll
  for (int j = 0; j < 4; ++j) {
    int row = ty + j * 8;
    tile[row][tx] = in[(size_t)(k0 + row) * N + n0 + tx];
  }
  __syncthreads();
#pragma unroll
  for (int j = 0; j < 4; ++j) {
    int row = ty + j * 8;
    out[(size_t)(n0 + row) * K + k0 + tx] = tobf(tile[tx][row]);
  }
}

// ---------------- GEMM: C[M,N] = A[M,K] * Bt[N,K]^T  (bf16 in, f32 acc) ---
template <int EPI>
__global__ __launch_bounds__(256) void gemm_bt(
    const u16* __restrict__ A, const u16* __restrict__ Bt,
    const float* __restrict__ bias,
    u16* __restrict__ o0, u16* __restrict__ o1, u16* __restrict__ o2,
    float* __restrict__ fo, int M, int N, int K) {
  __shared__ __align__(16) u16 As[128 * 64];
  __shared__ __align__(16) u16 Bs[128 * 64];
  const int tid = threadIdx.x;
  const int lane = tid & 63;
  const int wave = tid >> 6;
  const int nbn = N >> 7;
  const int bm = (int)blockIdx.x / nbn, bn = (int)blockIdx.x % nbn;
  const int m0 = bm << 7, n0 = bn << 7;
  const int wr = wave >> 1, wc = wave & 1;
  const int r15 = lane & 15, g = lane >> 4;

  f32x4 acc[4][4] = {};

  const int nkt = K >> 6;
  for (int kt = 0; kt < nkt; ++kt) {
#pragma unroll
    for (int j = 0; j < 4; ++j) {
      int c = j * 4 + wave;
      int byte0 = c * 1024 + lane * 16;
      int row = byte0 >> 7;
      int colb = (byte0 & 127) ^ ((row & 7) << 4);
      gload_lds16(A + (size_t)(m0 + row) * K + kt * 64 + (colb >> 1),
                  (char*)As + c * 1024);
      gload_lds16(Bt + (size_t)(n0 + row) * K + kt * 64 + (colb >> 1),
                  (char*)Bs + c * 1024);
    }
    __syncthreads();
#pragma unroll
    for (int kk = 0; kk < 64; kk += 32) {
      bf16x8 af[4], bf[4];
#pragma unroll
      for (int i = 0; i < 4; ++i) {
        int rowA = wr * 64 + i * 16 + r15;
        int ca = (kk * 2 + 16 * g) ^ ((rowA & 7) << 4);
        af[i] = *(const bf16x8*)((const char*)As + rowA * 128 + ca);
        int rowB = wc * 64 + i * 16 + r15;
        int cb = (kk * 2 + 16 * g) ^ ((rowB & 7) << 4);
        bf[i] = *(const bf16x8*)((const char*)Bs + rowB * 128 + cb);
      }
#pragma unroll
      for (int i = 0; i < 4; ++i)
#pragma unroll
        for (int j2 = 0; j2 < 4; ++j2)
          acc[i][j2] = __builtin_amdgcn_mfma_f32_16x16x32_bf16(
              af[i], bf[j2], acc[i][j2], 0, 0, 0);
    }
    __syncthreads();
  }
#pragma unroll
  for (int j2 = 0; j2 < 4; ++j2) {
    int n = n0 + wc * 64 + j2 * 16 + r15;
    float bv = bias[n];
#pragma unroll
    for (int i = 0; i < 4; ++i) {
      int mbase = m0 + wr * 64 + i * 16 + g * 4;
#pragma unroll
      for (int rr = 0; rr < 4; ++rr) {
        float val = acc[i][j2][rr] + bv;
        int m = mbase + rr;
        if (EPI == 0) {
          u16 hv = tobf(val);
          int b = m >> 11, t = m & 2047;
          int sec = n >> 10, nn = n & 1023;
          int h = nn >> 6, d = nn & 63;
          if (sec == 0)
            o0[((size_t)((b * 16 + h) * 2048 + t)) * 64 + d] = hv;
          else if (sec == 1)
            o1[((size_t)((b * 16 + h) * 2048 + t)) * 64 + d] = hv;
          else
            o2[((size_t)((b * 16 + h) * 64 + d)) * 2048 + t] = hv;
        } else {
          fo[(size_t)m * N + n] = val;
        }
      }
    }
  }
}

// ---------------- causal flash attention v3 -------------------------------
// 256 thr / 4 waves; wave owns 16 q-rows (64 q/block); KV tiles 64; dbuf
// staging; heavy-first grid of 1024 blocks (3 resident/CU + HW backfill =
// LPT balance); deferred-sum softmax (per-lane partials, one reduce at end);
// defer-max (THR=8, log2 domain); setprio around MFMA.
__global__ __launch_bounds__(256) void attn_kernel(
    const u16* __restrict__ qb, const u16* __restrict__ kb,
    const u16* __restrict__ vt, u16* __restrict__ yb) {
  __shared__ __align__(16) u16 Ks[2][64 * 64];
  __shared__ __align__(16) u16 Vs[2][64 * 64];
  __shared__ __align__(16) u16 Ps[4][16 * 80];
  const int tid = threadIdx.x;
  const int lane = tid & 63;
  const int w = tid >> 6;                       // 0..3
  const int r15 = lane & 15, g = lane >> 4;
  const int bx = blockIdx.x;
  const int c = 31 - (bx >> 5);                 // heavy chunks first
  const int bh = bx & 31;

  const int qmin = c * 64 + w * 16;             // wave's first q row
  const int qmax = qmin + 15;
  const int nt = c + 1;                         // KV tiles to process

  // staging: thread covers rows (tid>>3) and (tid>>3)+32, 16B each,
  // pre-swizzled source so linear LDS dest + XOR read agree.
  const int srow = tid >> 3;                    // 0..31
  const int scolb = ((tid & 7) * 16) ^ ((srow & 7) << 4);  // row&7 == (row+32)&7
  const u16* ksrc = kb + ((size_t)bh * 2048 + srow) * 64 + (scolb >> 1);
  const u16* vsrc = vt + ((size_t)bh * 64 + srow) * 2048 + (scolb >> 1);

#define STAGE(buf, kt)                                                     \
  do {                                                                     \
    gload_lds16(ksrc + (size_t)(kt) * 4096, (char*)Ks[buf] + w * 1024);    \
    gload_lds16(ksrc + (size_t)(kt) * 4096 + 32 * 64,                      \
                (char*)Ks[buf] + 4096 + w * 1024);                         \
    gload_lds16(vsrc + (kt) * 64, (char*)Vs[buf] + w * 1024);              \
    gload_lds16(vsrc + (kt) * 64 + 32 * 2048,                              \
                (char*)Vs[buf] + 4096 + w * 1024);                         \
  } while (0)

  // Q fragments (regs all kernel)
  const u16* qrow = qb + ((size_t)bh * 2048 + qmin + r15) * 64;
  bf16x8 aq[2];
  aq[0] = *(const bf16x8*)(qrow + 8 * g);
  aq[1] = *(const bf16x8*)(qrow + 32 + 8 * g);

  f32x4 o[4] = {};
  float mrow[4] = {-INFINITY, -INFINITY, -INFINITY, -INFINITY};
  float lrow[4] = {0.f, 0.f, 0.f, 0.f};  // per-lane PARTIAL sums

  STAGE(0, 0);
  __syncthreads();
  int cur = 0;
  for (int kt = 0; kt < nt; ++kt) {
    if (kt + 1 < nt) STAGE(cur ^ 1, kt + 1);
    if (kt * 64 <= qmax) {
      const char* Kc = (const char*)Ks[cur];
      const char* Vc = (const char*)Vs[cur];
      // S = Q K^T ; lane holds q=(g*4+rr), kv=nb*16+r15
      f32x4 s[4] = {};
      __builtin_amdgcn_s_setprio(1);
#pragma unroll
      for (int kk = 0; kk < 2; ++kk) {
#pragma unroll
        for (int nb = 0; nb < 4; ++nb) {
          int rowK = nb * 16 + r15;
          int cb = (kk * 64 + 16 * g) ^ ((rowK & 7) << 4);
          bf16x8 bk = *(const bf16x8*)(Kc + rowK * 128 + cb);
          s[nb] = __builtin_amdgcn_mfma_f32_16x16x32_bf16(aq[kk], bk, s[nb], 0, 0, 0);
        }
      }
      __builtin_amdgcn_s_setprio(0);

      const bool anymask = (kt * 64 + 63 > qmin);
      float p[4][4];
      float mt[4] = {-INFINITY, -INFINITY, -INFINITY, -INFINITY};
#pragma unroll
      for (int nb = 0; nb < 4; ++nb) {
#pragma unroll
        for (int rr = 0; rr < 4; ++rr) {
          float sv = s[nb][rr] * SM_SCALE;  // log2-domain
          if (anymask) {
            int kvg = kt * 64 + nb * 16 + r15;
            int qg = qmin + g * 4 + rr;
            if (kvg > qg) sv = -INFINITY;
          }
          p[nb][rr] = sv;
          mt[rr] = fmaxf(mt[rr], sv);
        }
      }
      // cross-lane row-max (needed before exp); sum stays per-lane
#pragma unroll
      for (int rr = 0; rr < 4; ++rr) {
        float v = mt[rr];
        v = fmaxf(v, __shfl_xor(v, 1, 64));
        v = fmaxf(v, __shfl_xor(v, 2, 64));
        v = fmaxf(v, __shfl_xor(v, 4, 64));
        v = fmaxf(v, __shfl_xor(v, 8, 64));
        mt[rr] = v;
      }
      // defer-max: only rescale when a row grew by > 8 (log2-domain)
      bool grew = false;
#pragma unroll
      for (int rr = 0; rr < 4; ++rr) grew |= (mt[rr] > mrow[rr] + 8.f);
      if (__any(grew)) {
#pragma unroll
        for (int rr = 0; rr < 4; ++rr) {
          float mnew = fmaxf(mrow[rr], mt[rr]);
          float alpha = exp2f(mrow[rr] - mnew);
          mrow[rr] = mnew;
          lrow[rr] *= alpha;
#pragma unroll
          for (int db = 0; db < 4; ++db) o[db][rr] *= alpha;
        }
      }
      u16* pw = &Ps[w][0];
#pragma unroll
      for (int rr = 0; rr < 4; ++rr) {
#pragma unroll
        for (int nb = 0; nb < 4; ++nb) {
          float pv = exp2f(p[nb][rr] - mrow[rr]);
          lrow[rr] += pv;  // per-lane partial, no shuffle
          pw[(g * 4 + rr) * 80 + nb * 16 + r15] = tobf(pv);
        }
      }
      // PV: o += P * V
      __builtin_amdgcn_s_setprio(1);
#pragma unroll
      for (int kk = 0; kk < 2; ++kk) {
        bf16x8 ap = *(const bf16x8*)((const char*)pw + r15 * 160 + kk * 64 + 16 * g);
#pragma unroll
        for (int db = 0; db < 4; ++db) {
          int rowV = db * 16 + r15;
          int cb = (kk * 64 + 16 * g) ^ ((rowV & 7) << 4);
          bf16x8 bv = *(const bf16x8*)(Vc + rowV * 128 + cb);
          o[db] = __builtin_amdgcn_mfma_f32_16x16x32_bf16(ap, bv, o[db], 0, 0, 0);
        }
      }
      __builtin_amdgcn_s_setprio(0);
    }
    __syncthreads();
    cur ^= 1;
  }
#undef STAGE

  // final cross-lane sum reduce (once per kernel)
#pragma unroll
  for (int rr = 0; rr < 4; ++rr) {
    float v = lrow[rr];
    v += __shfl_xor(v, 1, 64);
    v += __shfl_xor(v, 2, 64);
    v += __shfl_xor(v, 4, 64);
    v += __shfl_xor(v, 8, 64);
    lrow[rr] = 1.0f / v;
  }

  // epilogue: y[b, t, h*64+d] bf16
  int b = bh >> 4, h = bh & 15;
#pragma unroll
  for (int db = 0; db < 4; ++db) {
#pragma unroll
    for (int rr = 0; rr < 4; ++rr) {
      int t = qmin + g * 4 + rr;
      int col = h * 64 + db * 16 + r15;
      yb[((size_t)b * 2048 + t) * 1024 + col] = tobf(o[db][rr] * lrow[rr]);
    }
  }
}

extern "C" void kernel_launch(void* const* d_in, const int* in_sizes, int n_in,
                              void* d_out, int out_size, void* d_ws,
                              size_t ws_size, hipStream_t stream) {
  const float* x = (const float*)d_in[0];
  const float* w_attn = (const float*)d_in[1];
  const float* b_attn = (const float*)d_in[2];
  const float* w_proj = (const float*)d_in[3];
  const float* b_proj = (const float*)d_in[4];
  float* out = (float*)d_out;
  char* ws = (char*)d_ws;

  u16* xb = (u16*)ws;                          // 8 MB  [4096][1024]
  u16* wat = (u16*)(ws + (8ull << 20));        // 6 MB  [3072][1024]
  u16* wpt = (u16*)(ws + (14ull << 20));       // 2 MB  [1024][1024]
  u16* qbuf = (u16*)(ws + (16ull << 20));      // 8 MB  [B,H,T,D]
  u16* kbuf = (u16*)(ws + (24ull << 20));      // 8 MB  [B,H,T,D]
  u16* vtb = (u16*)(ws + (32ull << 20));       // 8 MB  [B,H,D,T]
  u16* yb = (u16*)(ws + (40ull << 20));        // 8 MB  [4096][1024]

  convert_f32_bf16<<<2048, 256, 0, stream>>>(x, xb, (4096 * 1024) / 8);
  transpose_w<<<3072, 256, 0, stream>>>(w_attn, wat, 1024, 3072);
  transpose_w<<<1024, 256, 0, stream>>>(w_proj, wpt, 1024, 1024);
  gemm_bt<0><<<32 * 24, 256, 0, stream>>>(xb, wat, b_attn, qbuf, kbuf, vtb,
                                          nullptr, 4096, 3072, 1024);
  attn_kernel<<<1024, 256, 0, stream>>>(qbuf, kbuf, vtb, yb);
  gemm_bt<1><<<32 * 8, 256, 0, stream>>>(yb, wpt, b_proj, nullptr, nullptr,
                                         nullptr, out, 4096, 1024, 1024);
}